// Round 8
// baseline (116.697 us; speedup 1.0000x reference)
//
#include <hip/hip_runtime.h>
#include <stdint.h>

#define NTETS   200000
#define FEATS   128
#define OUTF    128
#define NG      5
#define BM      128
#define NTHR    512
#define NBLOCKS ((NTETS + BM - 1) / BM)

typedef __attribute__((ext_vector_type(8))) short  short8v;
typedef __attribute__((ext_vector_type(4))) float  f32x4;

static __device__ __forceinline__ unsigned short bf16_rne(float f) {
  union { float f; unsigned u; } v; v.f = f;
  unsigned r = v.u + 0x7FFFu + ((v.u >> 16) & 1u);
  return (unsigned short)(r >> 16);
}

static __device__ __forceinline__ void gload_lds16(const void* g, void* l) {
  __builtin_amdgcn_global_load_lds(
      (const __attribute__((address_space(1))) unsigned int*)g,
      (__attribute__((address_space(3))) unsigned int*)l, 16, 0, 0);
}

// Detect int64-vs-int32 storage of neighbor indices (deterministic for fixed input).
__global__ void detect_mode_k(const int* __restrict__ nbr, int* __restrict__ flag) {
  int t = threadIdx.x;
  int nz = 0;
  for (int i = t; i < 4096; i += 64) nz |= nbr[2 * i + 1];
  unsigned long long any = __ballot(nz != 0);
  if (t == 0) flag[0] = (any == 0ULL) ? 1 : 0;   // 1 => int64 indices
}

// W fp32 [128][640] -> fragment-ordered bf16 image [g][kk][ns8][lane64][e8]:
// lane l's 16B at byte offset ((g*32+kk*8+ns)*1024 + l*16) holds
// W[n = ns*16 + (l&15)][k = g*128 + kk*32 + (l>>4)*8 + e]  — exactly the
// mfma_16x16x32 B-fragment, so the wave's LDS read is 1KB contiguous.
__global__ void prep_wfrag_k(const float* __restrict__ W, unsigned short* __restrict__ wf) {
  int id = blockIdx.x * 256 + threadIdx.x;
  if (id >= NG * 16384) return;
  int e  = id & 7;
  int l6 = (id >> 3) & 63;
  int ns = (id >> 9) & 7;
  int kk = (id >> 12) & 3;
  int g  = id >> 14;
  int n = ns * 16 + (l6 & 15);
  int k = g * 128 + kk * 32 + (l6 >> 4) * 8 + e;
  wf[id] = bf16_rne(W[n * (NG * FEATS) + k]);
}

// features fp32 -> linear bf16 image (coalesced stream, 8 elems/thread).
__global__ __launch_bounds__(256) void prep_f_k(const float* __restrict__ feat,
                                                unsigned short* __restrict__ fimg) {
  size_t i = ((size_t)blockIdx.x * 256 + threadIdx.x) * 8;
  f32x4 a = *(const f32x4*)(feat + i);
  f32x4 b = *(const f32x4*)(feat + i + 4);
  short8v v;
  v[0] = (short)bf16_rne(a[0]); v[1] = (short)bf16_rne(a[1]);
  v[2] = (short)bf16_rne(a[2]); v[3] = (short)bf16_rne(a[3]);
  v[4] = (short)bf16_rne(b[0]); v[5] = (short)bf16_rne(b[1]);
  v[6] = (short)bf16_rne(b[2]); v[7] = (short)bf16_rne(b[3]);
  *(short8v*)(fimg + i) = v;
}

__global__ __launch_bounds__(NTHR, 4) void conv_k(
    const unsigned short* __restrict__ fimg, const int* __restrict__ nbr,
    const float* __restrict__ bias, const unsigned short* __restrict__ wf,
    const int* __restrict__ mode, float* __restrict__ out)
{
  __shared__ __align__(16) char wtile[2][32768];   // W chunks only, double-buffered
  __shared__ unsigned srcoff[NG][BM];

  const int t    = threadIdx.x;
  const int row0 = blockIdx.x * BM;
  const int lane = t & 63;
  const int wv   = t >> 6;          // 8 waves; wave wv owns rows [wv*16, wv*16+16)
  const int lr   = lane & 15;
  const int lk   = lane >> 4;

  // ---- per-block source byte-offsets into fimg ----
  {
    const bool m64 = (mode[0] != 0);
    for (int e = t; e < NG * BM; e += NTHR) {
      int g = e >> 7, r = e & (BM - 1);
      int gr = row0 + r;
      int s = 0;
      if (gr < NTETS) {
        if (g == 0) s = gr;
        else {
          size_t idx = (size_t)gr * 4 + (g - 1);
          s = m64 ? nbr[2 * idx] : nbr[idx];
          if ((unsigned)s >= (unsigned)NTETS) s = 0;
        }
      }
      srcoff[g][r] = (unsigned)s * 256u;
    }
  }
  __syncthreads();

  // per-lane A-fragment base offsets: lane l gathers row (wv*16 + (l&15)),
  // bytes [kk*64 + lk*16, +16) — EXACTLY the mfma_16x16x32 A-fragment.
  const char* fimgc = (const char*)fimg;
  unsigned aoff[NG];
#pragma unroll
  for (int g = 0; g < NG; ++g)
    aoff[g] = srcoff[g][wv * 16 + lr] + (unsigned)(lk * 16);

  const f32x4 zero = {0.f, 0.f, 0.f, 0.f};
  f32x4 acc[8];
#pragma unroll
  for (int i = 0; i < 8; ++i) acc[i] = zero;

  short8v a[2][4];   // A-fragment double buffer [chunk parity][kk]

#define SB() __builtin_amdgcn_sched_barrier(0)

#define A_ISSUE(gg) do {                                                        \
    _Pragma("unroll")                                                           \
    for (int kk_ = 0; kk_ < 4; ++kk_)                                           \
      a[(gg) & 1][kk_] = *(const short8v*)(fimgc + aoff[gg] + kk_ * 64);        \
  } while (0)

#define W_ISSUE(gg) do {                                                        \
    const char* ws_ = (const char*)wf + (gg) * 32768 + wv * 4096 + (lane << 4); \
    _Pragma("unroll")                                                           \
    for (int i_ = 0; i_ < 4; ++i_)                                              \
      gload_lds16(ws_ + i_ * 1024, &wtile[(gg) & 1][wv * 4096 + i_ * 1024]);    \
  } while (0)

  // ---- prologue: A depth-1, W depth-2 ----
  A_ISSUE(0); SB();
  W_ISSUE(0); SB();
  W_ISSUE(1); SB();
  asm volatile("s_waitcnt vmcnt(4)" ::: "memory");  // A(0)+W(0) retired, W(1) in flight
  SB();
  __builtin_amdgcn_s_barrier();

#pragma unroll
  for (int g = 0; g < NG; ++g) {
    const int bi = g & 1;
    // A(g+1) prefetch (registers; consumed next chunk; compiler-tracked waits)
    if (g + 1 < NG) { A_ISSUE(g + 1); }
    SB();
#pragma unroll
    for (int kk = 0; kk < 4; ++kk) {
      short8v b[8];
#pragma unroll
      for (int ns = 0; ns < 8; ++ns)
        b[ns] = *(const short8v*)(&wtile[bi][(kk * 8 + ns) * 1024 + (lane << 4)]);
      if (kk == 3 && g + 2 < NG) {
        // all waves done reading wtile[bi] -> safe to start W(g+2) DMA into it
        asm volatile("s_waitcnt lgkmcnt(0)" ::: "memory");
        SB();
        __builtin_amdgcn_s_barrier();
        W_ISSUE(g + 2);
        SB();
      }
#pragma unroll
      for (int ns = 0; ns < 8; ++ns)
        acc[ns] = __builtin_amdgcn_mfma_f32_16x16x32_bf16(a[bi][kk], b[ns], acc[ns], 0, 0, 0);
    }
    SB();
    // publish W(g+1) before the next chunk reads it (counted: A/W prefetches stay in flight)
    if (g <= 2) {
      asm volatile("s_waitcnt vmcnt(8)" ::: "memory");  // retires W(g+1); A(g+1),W(g+2) in flight
      SB();
      __builtin_amdgcn_s_barrier();
    } else if (g == 3) {
      asm volatile("s_waitcnt vmcnt(4)" ::: "memory");  // W(4) landed, A(4) in flight
      SB();
      __builtin_amdgcn_s_barrier();
    }
  }

  // ---- epilogue: bias + relu + fp32 store (C: col=lane&15, row=(lane>>4)*4+reg) ----
#pragma unroll
  for (int ns = 0; ns < 8; ++ns) {
    const int col = ns * 16 + lr;
    const float bv = bias[col];
    const int rbase = row0 + wv * 16 + lk * 4;
#pragma unroll
    for (int i = 0; i < 4; ++i) {
      int r = rbase + i;
      if (r < NTETS) {
        float vv = acc[ns][i] + bv;
        out[(size_t)r * OUTF + col] = vv > 0.f ? vv : 0.f;
      }
    }
  }
#undef A_ISSUE
#undef W_ISSUE
#undef SB
}

extern "C" void kernel_launch(void* const* d_in, const int* in_sizes, int n_in,
                              void* d_out, int out_size, void* d_ws, size_t ws_size,
                              hipStream_t stream) {
  const float* feat = (const float*)d_in[0];
  const int*   nbr  = (const int*)d_in[1];
  const float* W    = (const float*)d_in[2];
  const float* bias = (const float*)d_in[3];
  float* out = (float*)d_out;

  int* mode = (int*)d_ws;
  unsigned short* wf   = (unsigned short*)((char*)d_ws + 1024);       // 160 KB frag image
  unsigned short* fimg = (unsigned short*)((char*)d_ws + 164864);     // 51.2 MB bf16 features

  detect_mode_k<<<1, 64, 0, stream>>>(nbr, mode);
  prep_wfrag_k<<<320, 256, 0, stream>>>(W, wf);
  prep_f_k<<<(NTETS * FEATS / 8 + 255) / 256, 256, 0, stream>>>(feat, fimg);
  conv_k<<<NBLOCKS, NTHR, 0, stream>>>(fimg, nbr, bias, wf, mode, out);
}

// Round 9
// 111.391 us; speedup vs baseline: 1.0476x; 1.0476x over previous
//
#include <hip/hip_runtime.h>
#include <stdint.h>

#define NTETS   200000
#define FEATS   128
#define OUTF    128
#define NG      5
#define BM      128
#define NTHR    512
#define NBLOCKS ((NTETS + BM - 1) / BM)
#define SUBS    10        // K=64 sub-chunks (2 per gather slot)
#define SUBW    16384     // W bytes per sub-chunk (16 frags x 1KB)

typedef __attribute__((ext_vector_type(8))) short  short8v;
typedef __attribute__((ext_vector_type(4))) float  f32x4;

static __device__ __forceinline__ unsigned short bf16_rne(float f) {
  union { float f; unsigned u; } v; v.f = f;
  unsigned r = v.u + 0x7FFFu + ((v.u >> 16) & 1u);
  return (unsigned short)(r >> 16);
}

static __device__ __forceinline__ void gload_lds16(const void* g, void* l) {
  __builtin_amdgcn_global_load_lds(
      (const __attribute__((address_space(1))) unsigned int*)g,
      (__attribute__((address_space(3))) unsigned int*)l, 16, 0, 0);
}

// Detect int64-vs-int32 storage of neighbor indices (deterministic for fixed input).
__global__ void detect_mode_k(const int* __restrict__ nbr, int* __restrict__ flag) {
  int t = threadIdx.x;
  int nz = 0;
  for (int i = t; i < 4096; i += 64) nz |= nbr[2 * i + 1];
  unsigned long long any = __ballot(nz != 0);
  if (t == 0) flag[0] = (any == 0ULL) ? 1 : 0;   // 1 => int64 indices
}

// W fp32 [128][640] -> fragment-ordered bf16 image [g][kk][ns8][lane64][e8]:
// byte ((g*4+kk)*8+ns)*1024 + lane*16 = lane's mfma_16x16x32 B-fragment
// (n = ns*16 + (lane&15), k = g*128 + kk*32 + (lane>>4)*8 + e).
__global__ void prep_wfrag_k(const float* __restrict__ W, unsigned short* __restrict__ wf) {
  int id = blockIdx.x * 256 + threadIdx.x;
  if (id >= NG * 16384) return;
  int e  = id & 7;
  int l6 = (id >> 3) & 63;
  int ns = (id >> 9) & 7;
  int kk = (id >> 12) & 3;
  int g  = id >> 14;
  int n = ns * 16 + (l6 & 15);
  int k = g * 128 + kk * 32 + (l6 >> 4) * 8 + e;
  wf[id] = bf16_rne(W[n * (NG * FEATS) + k]);
}

// features fp32 -> linear bf16 image; nt loads keep fp32 feat out of L3.
__global__ __launch_bounds__(256) void prep_f_k(const float* __restrict__ feat,
                                                unsigned short* __restrict__ fimg) {
  size_t i = ((size_t)blockIdx.x * 256 + threadIdx.x) * 8;
  f32x4 a = __builtin_nontemporal_load((const f32x4*)(feat + i));
  f32x4 b = __builtin_nontemporal_load((const f32x4*)(feat + i + 4));
  short8v v;
  v[0] = (short)bf16_rne(a[0]); v[1] = (short)bf16_rne(a[1]);
  v[2] = (short)bf16_rne(a[2]); v[3] = (short)bf16_rne(a[3]);
  v[4] = (short)bf16_rne(b[0]); v[5] = (short)bf16_rne(b[1]);
  v[6] = (short)bf16_rne(b[2]); v[7] = (short)bf16_rne(b[3]);
  *(short8v*)(fimg + i) = v;
}

__global__ __launch_bounds__(NTHR, 6) void conv_k(
    const unsigned short* __restrict__ fimg, const int* __restrict__ nbr,
    const float* __restrict__ bias, const unsigned short* __restrict__ wf,
    const int* __restrict__ mode, float* __restrict__ out)
{
  __shared__ __align__(16) char wtile[3][SUBW];   // W sub-chunks, triple-buffered ring
  __shared__ unsigned srcoff[NG][BM];

  const int t    = threadIdx.x;
  const int row0 = blockIdx.x * BM;
  const int lane = t & 63;
  const int wv   = t >> 6;          // 8 waves; wave wv owns rows [wv*16, wv*16+16)
  const int lr   = lane & 15;
  const int lk   = lane >> 4;

  // ---- per-block source byte-offsets into fimg ----
  {
    const bool m64 = (mode[0] != 0);
    for (int e = t; e < NG * BM; e += NTHR) {
      int g = e >> 7, r = e & (BM - 1);
      int gr = row0 + r;
      int s = 0;
      if (gr < NTETS) {
        if (g == 0) s = gr;
        else {
          size_t idx = (size_t)gr * 4 + (g - 1);
          s = m64 ? nbr[2 * idx] : nbr[idx];
          if ((unsigned)s >= (unsigned)NTETS) s = 0;
        }
      }
      srcoff[g][r] = (unsigned)s * 256u;
    }
  }
  __syncthreads();

  // lane l's A-fragment: row (wv*16 + (l&15)), bytes [kk*64 + (l>>4)*16, +16).
  const char* fimgc = (const char*)fimg;
  unsigned aoff[NG];
#pragma unroll
  for (int g = 0; g < NG; ++g)
    aoff[g] = srcoff[g][wv * 16 + lr] + (unsigned)(lk * 16);

  const f32x4 zero = {0.f, 0.f, 0.f, 0.f};
  f32x4 acc[8];
#pragma unroll
  for (int i = 0; i < 8; ++i) acc[i] = zero;

  short8v a[3][2];   // A-fragment ring [sub%3][kklo]

#define SB() __builtin_amdgcn_sched_barrier(0)

  // sub ss covers k-slices kk = 2*(ss&1) + {0,1} of gather slot g = ss>>1
#define A_ISSUE(ss) do {                                                          \
    a[(ss) % 3][0] = *(const short8v*)(fimgc + aoff[(ss) >> 1] +                  \
                                       (((ss) & 1) * 2 + 0) * 64);                \
    a[(ss) % 3][1] = *(const short8v*)(fimgc + aoff[(ss) >> 1] +                  \
                                       (((ss) & 1) * 2 + 1) * 64);                \
  } while (0)

  // wave stages 2KB of the 16KB sub-chunk; LDS dest wave-uniform, src per-lane
#define W_ISSUE(ss) do {                                                          \
    const char* ws_ = (const char*)wf + (size_t)(ss) * SUBW + wv * 2048 +         \
                      (lane << 4);                                                \
    char* wd_ = &wtile[(ss) % 3][wv * 2048];                                      \
    gload_lds16(ws_, wd_);                                                        \
    gload_lds16(ws_ + 1024, wd_ + 1024);                                          \
  } while (0)

  // ---- prologue: queue = [W0,A0,W1,A1]; retire W0,A0 ----
  W_ISSUE(0); SB();
  A_ISSUE(0); SB();
  W_ISSUE(1); SB();
  A_ISSUE(1); SB();
  asm volatile("s_waitcnt vmcnt(4)" ::: "memory");
  SB();
  __builtin_amdgcn_s_barrier();

#pragma unroll
  for (int s = 0; s < SUBS; ++s) {
    // issue 2-ahead: W into ring slot (s+2)%3 (its readers finished at sub s-1),
    // A into reg ring slot (s+2)%3
    if (s + 2 < SUBS) {
      W_ISSUE(s + 2); SB();
      A_ISSUE(s + 2); SB();
    }
    // compute sub s from wtile[s%3] (b-LDS waits are compiler-counted)
    {
      short8v b[8];
#pragma unroll
      for (int ns = 0; ns < 8; ++ns)
        b[ns] = *(const short8v*)(&wtile[s % 3][ns * 1024 + (lane << 4)]);
#pragma unroll
      for (int ns = 0; ns < 8; ++ns)
        acc[ns] = __builtin_amdgcn_mfma_f32_16x16x32_bf16(a[s % 3][0], b[ns], acc[ns], 0, 0, 0);
#pragma unroll
      for (int ns = 0; ns < 8; ++ns)
        b[ns] = *(const short8v*)(&wtile[s % 3][(8 + ns) * 1024 + (lane << 4)]);
#pragma unroll
      for (int ns = 0; ns < 8; ++ns)
        acc[ns] = __builtin_amdgcn_mfma_f32_16x16x32_bf16(a[s % 3][1], b[ns], acc[ns], 0, 0, 0);
    }
    SB();
    // retire {W(s+1), A(s+1)} (leaves {W(s+2), A(s+2)} in flight); publish via barrier
    if (s + 1 < SUBS) {
      if (s + 2 < SUBS) asm volatile("s_waitcnt vmcnt(4)" ::: "memory");
      else              asm volatile("s_waitcnt vmcnt(0)" ::: "memory");
      SB();
      __builtin_amdgcn_s_barrier();
    }
  }

  // ---- epilogue: bias + relu + nt fp32 store (C: col=lane&15, row=(lane>>4)*4+reg) ----
#pragma unroll
  for (int ns = 0; ns < 8; ++ns) {
    const int col = ns * 16 + lr;
    const float bv = bias[col];
    const int rbase = row0 + wv * 16 + lk * 4;
#pragma unroll
    for (int i = 0; i < 4; ++i) {
      int r = rbase + i;
      if (r < NTETS) {
        float vv = acc[ns][i] + bv;
        vv = vv > 0.f ? vv : 0.f;
        __builtin_nontemporal_store(vv, &out[(size_t)r * OUTF + col]);
      }
    }
  }
#undef A_ISSUE
#undef W_ISSUE
#undef SB
}

extern "C" void kernel_launch(void* const* d_in, const int* in_sizes, int n_in,
                              void* d_out, int out_size, void* d_ws, size_t ws_size,
                              hipStream_t stream) {
  const float* feat = (const float*)d_in[0];
  const int*   nbr  = (const int*)d_in[1];
  const float* W    = (const float*)d_in[2];
  const float* bias = (const float*)d_in[3];
  float* out = (float*)d_out;

  int* mode = (int*)d_ws;
  unsigned short* wf   = (unsigned short*)((char*)d_ws + 1024);       // 160 KB frag image
  unsigned short* fimg = (unsigned short*)((char*)d_ws + 164864);     // 51.2 MB bf16 features

  detect_mode_k<<<1, 64, 0, stream>>>(nbr, mode);
  prep_wfrag_k<<<320, 256, 0, stream>>>(W, wf);
  prep_f_k<<<(NTETS * FEATS / 8 + 255) / 256, 256, 0, stream>>>(feat, fimg);
  conv_k<<<NBLOCKS, NTHR, 0, stream>>>(fimg, nbr, bias, wf, mode, out);
}